// Round 18
// baseline (543.138 us; speedup 1.0000x reference)
//
#include <hip/hip_runtime.h>
#include <hip/hip_bf16.h>
#include <math.h>

#define D_MODEL 512
#define N_LAYERS 4
#define SEQ 2048
#define BATCH 8
#define M_TOT (BATCH * SEQ)   // 16384
#define DFF 2048
#define HEAD_V 256
#define SC 32                 // scan chunk
#define NC (SEQ / SC)         // 64 chunks

typedef __hip_bfloat16 bf16;
typedef __bf16 bf16x8 __attribute__((ext_vector_type(8)));
typedef float f32x4 __attribute__((ext_vector_type(4)));

__device__ __forceinline__ unsigned short bfbits(float x) {
    bf16 h = __float2bfloat16(x);
    return *(unsigned short*)&h;
}
__device__ __forceinline__ unsigned int pk(float a, float b) {
    return (unsigned int)bfbits(a) | ((unsigned int)bfbits(b) << 16);
}

// fast GELU (sigmoid form): max abs err vs exact ~3e-3 (validated r9-r17, absmax 0.0156)
__device__ __forceinline__ float gelu_f(float x) {
    float t2 = 1.5957691216f * (x + 0.044715f * x * x * x);
    float e = __expf(t2);
    return x - x * __builtin_amdgcn_rcpf(e + 1.0f);
}

// ---------- weight convert + transpose: W (R x C) f32 -> WT (C x R) bf16 ----
__global__ void convT_kernel(const float* __restrict__ W, bf16* __restrict__ WT,
                             int R, int C, size_t wstride, size_t tstride) {
    W += (size_t)blockIdx.z * wstride;
    WT += (size_t)blockIdx.z * tstride;
    __shared__ float t[32][33];
    int r0 = blockIdx.x * 32, c0 = blockIdx.y * 32;
    int tx = threadIdx.x, ty = threadIdx.y;  // 32 x 8
    #pragma unroll
    for (int i = 0; i < 32; i += 8)
        t[ty + i][tx] = W[(size_t)(r0 + ty + i) * C + c0 + tx];
    __syncthreads();
    #pragma unroll
    for (int i = 0; i < 32; i += 8)
        WT[(size_t)(c0 + ty + i) * R + r0 + tx] = __float2bfloat16(t[tx][ty + i]);
}

// ---------- embedding: x f32 + x bf16 --------------------------------------
__global__ void embed_kernel(const int* __restrict__ tokens,
                             const float* __restrict__ emb,
                             float* __restrict__ xf, bf16* __restrict__ xb) {
    int row = blockIdx.x, t = threadIdx.x;  // 128 threads
    int tok = tokens[row];
    float4 v = ((const float4*)(emb + (size_t)tok * D_MODEL))[t];
    ((float4*)(xf + (size_t)row * D_MODEL))[t] = v;
    uint2 st; st.x = pk(v.x, v.y); st.y = pk(v.z, v.w);
    ((uint2*)(xb + (size_t)row * D_MODEL))[t] = st;
}

// ---------- 3-phase parallel masked scan over S -----------------------------
__global__ void scanA_kernel(bf16* __restrict__ u, const int* __restrict__ tokens,
                             const float* __restrict__ decayp,
                             float* __restrict__ L, float* __restrict__ P) {
    int idx = blockIdx.x;                 // B*NC*2 blocks
    int dblk = idx & 1;
    int c = (idx >> 1) & (NC - 1);
    int b = idx >> 7;                     // NC*2 = 128
    int d = dblk * 256 + threadIdx.x;
    float decay = 1.0f / (1.0f + __expf(-decayp[0]));
    const int* tok = tokens + (size_t)b * SEQ + c * SC;
    bf16* up = u + ((size_t)b * SEQ + (size_t)c * SC) * D_MODEL + d;
    float mem = 0.0f;
    #pragma unroll 4
    for (int s = 0; s < SC; ++s) {
        float ui = __bfloat162float(up[(size_t)s * D_MODEL]);
        bool m = (tok[s] != 0);
        mem = (m ? decay : 1.0f) * mem + (m ? ui : 0.0f);
        up[(size_t)s * D_MODEL] = __float2bfloat16(mem);
    }
    L[((size_t)b * NC + c) * D_MODEL + d] = mem;
    if (threadIdx.x == 0 && dblk == 0) {
        int cnt = 0;
        for (int s = 0; s < SC; ++s) cnt += (tok[s] != 0);
        P[b * NC + c] = __powf(decay, (float)cnt);
    }
}

__global__ void scanB_kernel(const float* __restrict__ L, const float* __restrict__ P,
                             float* __restrict__ Mc) {
    int b = blockIdx.x >> 1;              // B*2 blocks
    int d = (blockIdx.x & 1) * 256 + threadIdx.x;
    float carry = 0.0f;
    for (int c = 0; c < NC; ++c) {
        size_t off = ((size_t)b * NC + c) * D_MODEL + d;
        Mc[off] = carry;
        carry = P[b * NC + c] * carry + L[off];
    }
}

__global__ void scanC_kernel(bf16* __restrict__ u, const int* __restrict__ tokens,
                             const float* __restrict__ decayp,
                             const float* __restrict__ Mc) {
    int idx = blockIdx.x;
    int dblk = idx & 1;
    int c = (idx >> 1) & (NC - 1);
    int b = idx >> 7;
    if (c == 0) return;
    int d = dblk * 256 + threadIdx.x;
    float decay = 1.0f / (1.0f + __expf(-decayp[0]));
    const int* tok = tokens + (size_t)b * SEQ + c * SC;
    bf16* up = u + ((size_t)b * SEQ + (size_t)c * SC) * D_MODEL + d;
    float carry = Mc[((size_t)b * NC + c) * D_MODEL + d];
    float coeff = 1.0f;
    #pragma unroll 4
    for (int s = 0; s < SC; ++s) {
        bool m = (tok[s] != 0);
        coeff *= (m ? decay : 1.0f);
        float local = __bfloat162float(up[(size_t)s * D_MODEL]);
        up[(size_t)s * D_MODEL] = __float2bfloat16(local + carry * coeff);
    }
}

// ---------- LayerNorm body + non-template wrappers --------------------------
__device__ __forceinline__ void ln_body(const float* __restrict__ in,
                                        float* __restrict__ outf,
                                        bf16* __restrict__ outb,
                                        const float* __restrict__ g,
                                        const float* __restrict__ b,
                                        int WF, int WB) {
    int w = threadIdx.x >> 6, lane = threadIdx.x & 63;
    int row = blockIdx.x * 4 + w;
    const float4* ip = (const float4*)(in + (size_t)row * D_MODEL);
    float4 v0 = ip[lane * 2], v1 = ip[lane * 2 + 1];
    float s1 = v0.x + v0.y + v0.z + v0.w + v1.x + v1.y + v1.z + v1.w;
    float s2 = v0.x * v0.x + v0.y * v0.y + v0.z * v0.z + v0.w * v0.w +
               v1.x * v1.x + v1.y * v1.y + v1.z * v1.z + v1.w * v1.w;
    #pragma unroll
    for (int off = 32; off; off >>= 1) {
        s1 += __shfl_xor(s1, off);
        s2 += __shfl_xor(s2, off);
    }
    float mu = s1 * (1.0f / D_MODEL);
    float var = s2 * (1.0f / D_MODEL) - mu * mu;
    float rstd = rsqrtf(var + 1e-5f);
    const float4* g4 = (const float4*)g;
    const float4* b4 = (const float4*)b;
    float4 g0 = g4[lane * 2], g1 = g4[lane * 2 + 1];
    float4 b0 = b4[lane * 2], b1 = b4[lane * 2 + 1];
    float4 o0, o1;
    o0.x = (v0.x - mu) * rstd * g0.x + b0.x;
    o0.y = (v0.y - mu) * rstd * g0.y + b0.y;
    o0.z = (v0.z - mu) * rstd * g0.z + b0.z;
    o0.w = (v0.w - mu) * rstd * g0.w + b0.w;
    o1.x = (v1.x - mu) * rstd * g1.x + b1.x;
    o1.y = (v1.y - mu) * rstd * g1.y + b1.y;
    o1.z = (v1.z - mu) * rstd * g1.z + b1.z;
    o1.w = (v1.w - mu) * rstd * g1.w + b1.w;
    if (WF) {
        float4* op = (float4*)(outf + (size_t)row * D_MODEL);
        op[lane * 2] = o0; op[lane * 2 + 1] = o1;
    }
    if (WB) {
        uint4 st;
        st.x = pk(o0.x, o0.y); st.y = pk(o0.z, o0.w);
        st.z = pk(o1.x, o1.y); st.w = pk(o1.z, o1.w);
        ((uint4*)(outb + (size_t)row * D_MODEL))[lane] = st;
    }
}

__global__ void ln_b16_kernel(const float* __restrict__ in, bf16* __restrict__ outb,
                              const float* __restrict__ g, const float* __restrict__ b) {
    ln_body(in, nullptr, outb, g, b, 0, 1);
}

// Fused: xf = LN_norm(xf); lnb = LN_cms0(LN_norm(xf)).
__global__ void ln_fused_kernel(float* __restrict__ xf, bf16* __restrict__ outb,
                                const float* __restrict__ g0, const float* __restrict__ b0,
                                const float* __restrict__ g1, const float* __restrict__ b1) {
    int w = threadIdx.x >> 6, lane = threadIdx.x & 63;
    int row = blockIdx.x * 4 + w;
    float4* xp = (float4*)(xf + (size_t)row * D_MODEL);
    float4 v0 = xp[lane * 2], v1 = xp[lane * 2 + 1];
    float s1 = v0.x + v0.y + v0.z + v0.w + v1.x + v1.y + v1.z + v1.w;
    float s2 = v0.x * v0.x + v0.y * v0.y + v0.z * v0.z + v0.w * v0.w +
               v1.x * v1.x + v1.y * v1.y + v1.z * v1.z + v1.w * v1.w;
    #pragma unroll
    for (int off = 32; off; off >>= 1) {
        s1 += __shfl_xor(s1, off);
        s2 += __shfl_xor(s2, off);
    }
    float mu = s1 * (1.0f / D_MODEL);
    float var = s2 * (1.0f / D_MODEL) - mu * mu;
    float rstd = rsqrtf(var + 1e-5f);
    const float4* g4 = (const float4*)g0;
    const float4* b4 = (const float4*)b0;
    float4 ga = g4[lane * 2], gb = g4[lane * 2 + 1];
    float4 ba = b4[lane * 2], bb = b4[lane * 2 + 1];
    float4 o0, o1;
    o0.x = (v0.x - mu) * rstd * ga.x + ba.x;
    o0.y = (v0.y - mu) * rstd * ga.y + ba.y;
    o0.z = (v0.z - mu) * rstd * ga.z + ba.z;
    o0.w = (v0.w - mu) * rstd * ga.w + ba.w;
    o1.x = (v1.x - mu) * rstd * gb.x + bb.x;
    o1.y = (v1.y - mu) * rstd * gb.y + bb.y;
    o1.z = (v1.z - mu) * rstd * gb.z + bb.z;
    o1.w = (v1.w - mu) * rstd * gb.w + bb.w;
    xp[lane * 2] = o0; xp[lane * 2 + 1] = o1;
    float t1 = o0.x + o0.y + o0.z + o0.w + o1.x + o1.y + o1.z + o1.w;
    float t2 = o0.x * o0.x + o0.y * o0.y + o0.z * o0.z + o0.w * o0.w +
               o1.x * o1.x + o1.y * o1.y + o1.z * o1.z + o1.w * o1.w;
    #pragma unroll
    for (int off = 32; off; off >>= 1) {
        t1 += __shfl_xor(t1, off);
        t2 += __shfl_xor(t2, off);
    }
    float mu2 = t1 * (1.0f / D_MODEL);
    float var2 = t2 * (1.0f / D_MODEL) - mu2 * mu2;
    float rstd2 = rsqrtf(var2 + 1e-5f);
    const float4* g14 = (const float4*)g1;
    const float4* b14 = (const float4*)b1;
    float4 gc = g14[lane * 2], gd = g14[lane * 2 + 1];
    float4 bc = b14[lane * 2], bd = b14[lane * 2 + 1];
    float4 p0, p1;
    p0.x = (o0.x - mu2) * rstd2 * gc.x + bc.x;
    p0.y = (o0.y - mu2) * rstd2 * gc.y + bc.y;
    p0.z = (o0.z - mu2) * rstd2 * gc.z + bc.z;
    p0.w = (o0.w - mu2) * rstd2 * gc.w + bc.w;
    p1.x = (o1.x - mu2) * rstd2 * gd.x + bd.x;
    p1.y = (o1.y - mu2) * rstd2 * gd.y + bd.y;
    p1.z = (o1.z - mu2) * rstd2 * gd.z + bd.z;
    p1.w = (o1.w - mu2) * rstd2 * gd.w + bd.w;
    uint4 st;
    st.x = pk(p0.x, p0.y); st.y = pk(p0.z, p0.w);
    st.z = pk(p1.x, p1.y); st.w = pk(p1.z, p1.w);
    ((uint4*)(outb + (size_t)row * D_MODEL))[lane] = st;
}

// ---------- bf16 MFMA GEMM: r11 geometry + WM=32 small-GEMM variant ---------
// BN=256, 512 threads, 8 waves (2x4). WM = per-wave rows:
//   WM=128 -> BM=256 (W1)   WM=64 -> BM=128 (W2)   WM=32 -> BM=64 (small:
//   head grid 256 fills all CUs; fastmem grid 512 -> 2 blocks/CU, 80KB LDS)
// Per K-tile: STAGE(t+1) -> counted vmcnt (t's loads done, t+1's in flight)
// -> barrier -> ds_read + MFMA (setprio) -> barrier. 2 buffers.
// Swizzle: LDS row = 128B; 16B-slot s holds chunk s^(row&7); reads XOR same.
#define STAGE(buf, k0)                                                        \
    do {                                                                      \
        _Pragma("unroll")                                                     \
        for (int it = 0; it < AL; ++it) {                                     \
            int cc = tid + it * 512;                                          \
            int rr = cc >> 3, ss = cc & 7;                                    \
            __builtin_amdgcn_global_load_lds(                                 \
                A + (size_t)(m0 + rr) * K + (k0) + 8 * (ss ^ (rr & 7)),       \
                smem + (buf) * TILEB + cc * 16, 16, 0, 0);                    \
        }                                                                     \
        _Pragma("unroll")                                                     \
        for (int it = 0; it < 4; ++it) {                                      \
            int cc = tid + it * 512;                                          \
            int rr = cc >> 3, ss = cc & 7;                                    \
            __builtin_amdgcn_global_load_lds(                                 \
                BT + (size_t)(n0 + rr) * K + (k0) + 8 * (ss ^ (rr & 7)),      \
                smem + (buf) * TILEB + BM * 128 + cc * 16, 16, 0, 0);         \
        }                                                                     \
    } while (0)

template <int WM, int GELU, int RES, int OBF>
__device__ __forceinline__ void gemm_body(char* smem,
                          const bf16* __restrict__ A, const bf16* __restrict__ BT,
                          const float* __restrict__ bias, const float* __restrict__ R,
                          float* __restrict__ Cf, bf16* __restrict__ Cb,
                          int N, int K) {
    constexpr int BM = 2 * WM;
    constexpr int MI = WM / 16;               // m-frags per wave: 8, 4, or 2
    constexpr int MH = (MI >= 4) ? MI / 4 : 1;
    constexpr int MW = (MI >= 4) ? 4 : MI;    // frags per MFMA cluster
    constexpr int AL = (BM >= 64) ? BM / 64 : 1;  // A gload per thread per tile
    constexpr int TILEB = (BM + 256) * 128;   // bytes per LDS buffer
    constexpr int ST = 68;                    // epilogue LDS row stride (floats)
    const int tid = threadIdx.x;
    const int lane = tid & 63;
    const int w = tid >> 6;
    const int wr = w >> 2, wc = w & 3;        // 2 x 4 wave grid
    const int lm = lane & 15, lk = lane >> 4;
    const int swz = (lm & 7) << 4;
    const int m0 = blockIdx.x * BM, n0 = blockIdx.y * 256;

    f32x4 acc[MI][4] = {};
    const int nt = K >> 6;

    STAGE(0, 0);
    int cur = 0;
    for (int t = 0; t < nt; ++t) {
        if (t + 1 < nt) {
            STAGE(cur ^ 1, (t + 1) * 64);
            if constexpr (AL == 4)      asm volatile("s_waitcnt vmcnt(8)" ::: "memory");
            else if constexpr (AL == 2) asm volatile("s_waitcnt vmcnt(6)" ::: "memory");
            else                        asm volatile("s_waitcnt vmcnt(5)" ::: "memory");
        } else {
            asm volatile("s_waitcnt vmcnt(0)" ::: "memory");
        }
        __builtin_amdgcn_s_barrier();
        __builtin_amdgcn_sched_barrier(0);
        const char* Ab = smem + cur * TILEB;
        const char* Bb = Ab + BM * 128;
        #pragma unroll
        for (int ks = 0; ks < 2; ++ks) {
            bf16x8 fb[4];
            #pragma unroll
            for (int nf = 0; nf < 4; ++nf)
                fb[nf] = *(const bf16x8*)(Bb + (wc * 64 + nf * 16 + lm) * 128 +
                                          ((ks * 64 + lk * 16) ^ swz));
            #pragma unroll
            for (int mh = 0; mh < MH; ++mh) {
                bf16x8 fa[MW];
                #pragma unroll
                for (int mf = 0; mf < MW; ++mf)
                    fa[mf] = *(const bf16x8*)(Ab + (wr * WM + (mh * MW + mf) * 16 + lm) * 128 +
                                              ((ks * 64 + lk * 16) ^ swz));
                __builtin_amdgcn_s_setprio(1);
                #pragma unroll
                for (int mf = 0; mf < MW; ++mf)
                    #pragma unroll
                    for (int nf = 0; nf < 4; ++nf)
                        acc[mh * MW + mf][nf] = __builtin_amdgcn_mfma_f32_16x16x32_bf16(
                            fa[mf], fb[nf], acc[mh * MW + mf][nf], 0, 0, 0);
                __builtin_amdgcn_s_setprio(0);
            }
        }
        __builtin_amdgcn_s_barrier();
        cur ^= 1;
    }
    __syncthreads();

    // ---- epilogue: per-wave LDS round-trip for coalesced stores ----
    float* ep = (float*)smem + w * 16 * ST;
    const int r2 = lane >> 2;        // local row 0..15
    const int q = lane & 3;          // 16-col group
    const int gc0 = n0 + wc * 64 + q * 16;
    #pragma unroll
    for (int i = 0; i < MI; ++i) {
        #pragma unroll
        for (int nf = 0; nf < 4; ++nf)
            #pragma unroll
            for (int r = 0; r < 4; ++r)
                ep[(lk * 4 + r) * ST + nf * 16 + lm] = acc[i][nf][r];
        int grow = m0 + wr * WM + i * 16 + r2;
        float4 fx[4];
        #pragma unroll
        for (int v = 0; v < 4; ++v)
            fx[v] = *(const float4*)&ep[r2 * ST + q * 16 + v * 4];
        #pragma unroll
        for (int v = 0; v < 4; ++v) {
            float4 bb = *(const float4*)(bias + gc0 + v * 4);
            fx[v].x += bb.x; fx[v].y += bb.y; fx[v].z += bb.z; fx[v].w += bb.w;
            if (GELU) {
                fx[v].x = gelu_f(fx[v].x);
                fx[v].y = gelu_f(fx[v].y);
                fx[v].z = gelu_f(fx[v].z);
                fx[v].w = gelu_f(fx[v].w);
            }
            if (RES) {
                float4 rr = *(const float4*)(R + (size_t)grow * N + gc0 + v * 4);
                fx[v].x += rr.x; fx[v].y += rr.y; fx[v].z += rr.z; fx[v].w += rr.w;
            }
        }
        if (OBF == 0 || OBF == 2) {
            #pragma unroll
            for (int v = 0; v < 4; ++v)
                *(float4*)(Cf + (size_t)grow * N + gc0 + v * 4) = fx[v];
        }
        if (OBF >= 1) {
            uint4 s1, s2;
            s1.x = pk(fx[0].x, fx[0].y); s1.y = pk(fx[0].z, fx[0].w);
            s1.z = pk(fx[1].x, fx[1].y); s1.w = pk(fx[1].z, fx[1].w);
            s2.x = pk(fx[2].x, fx[2].y); s2.y = pk(fx[2].z, fx[2].w);
            s2.z = pk(fx[3].x, fx[3].y); s2.w = pk(fx[3].z, fx[3].w);
            *(uint4*)(Cb + (size_t)grow * N + gc0) = s1;
            *(uint4*)(Cb + (size_t)grow * N + gc0 + 8) = s2;
        }
    }
}

#define DEF_GEMM(name, WM, GELU, RES, OBF)                                    \
__launch_bounds__(512) __global__ void name(                                  \
        const bf16* __restrict__ A, const bf16* __restrict__ BT,              \
        const float* __restrict__ bias, const float* __restrict__ R,          \
        float* __restrict__ Cf, bf16* __restrict__ Cb, int N, int K) {        \
    __shared__ char smem[2 * ((2 * (WM)) + 256) * 128];                       \
    gemm_body<WM, GELU, RES, OBF>(smem, A, BT, bias, R, Cf, Cb, N, K);        \
}

DEF_GEMM(gemm_gelu,    128, 1, 0, 1)   // W1: 256x256, GELU, bf16 out
DEF_GEMM(gemm_u,        32, 0, 0, 1)   // fastmem u: 64x256, grid 512
DEF_GEMM(gemm_resf,     32, 0, 1, 0)   // fastmem residual: 64x256, grid 512
DEF_GEMM(gemm_res,      64, 0, 1, 0)   // W2: 128x256, f32 + residual
DEF_GEMM(gemm_resboth,  64, 0, 1, 2)   // last W2: residual, f32+bf16 out
DEF_GEMM(gemm_plain,    32, 0, 0, 0)   // head: 64x256, grid 256 (full GPU)

extern "C" void kernel_launch(void* const* d_in, const int* in_sizes, int n_in,
                              void* d_out, int out_size, void* d_ws, size_t ws_size,
                              hipStream_t stream) {
    const int*   tokens = (const int*)d_in[0];
    const float* emb    = (const float*)d_in[1];
    const float* W_upd  = (const float*)d_in[2];
    const float* b_upd  = (const float*)d_in[3];
    const float* W_f    = (const float*)d_in[4];
    const float* b_f    = (const float*)d_in[5];
    const float* decayp = (const float*)d_in[6];
    const float* norm_g = (const float*)d_in[7];
    const float* norm_b = (const float*)d_in[8];
    const float* cms_g  = (const float*)d_in[9];
    const float* cms_b  = (const float*)d_in[10];
    const float* cW1    = (const float*)d_in[11];
    const float* cb1    = (const float*)d_in[12];
    const float* cW2    = (const float*)d_in[13];
    const float* cb2    = (const float*)d_in[14];
    const float* head_W = (const float*)d_in[15];
    const float* head_b = (const float*)d_in[16];
    float* out = (float*)d_out;

    const int M = M_TOT, D = D_MODEL, F = DFF, V = HEAD_V;

    // ---- workspace layout ----
    float* xf = (float*)d_ws;                                   // 33.55 MB f32 residual
    bf16*  lnb = (bf16*)((char*)d_ws + (size_t)M * D * 4);      // 16.78 MB bf16 A-operand
    bf16*  wb  = (bf16*)((char*)lnb + (size_t)M * D * 2);       // 18.09 MB bf16 weights^T
    const size_t WB_ELEMS = 9043968;
    char* dyn = (char*)wb + WB_ELEMS * 2;
    size_t used = (size_t)(dyn - (char*)d_ws);
    size_t avail = ws_size > used ? ws_size - used : 0;
    int MC = 4096;
    if (avail >= (size_t)16384 * F * 2) MC = 16384;
    else if (avail >= (size_t)8192 * F * 2) MC = 8192;
    bf16* ub = (bf16*)dyn;   // fastmem u/mems (M x D bf16), dead before layers
    bf16* hb = (bf16*)dyn;   // hidden chunk (MC x F bf16)

    // scan scratch lives in d_out (head GEMM fully overwrites it later)
    float* scanL = out;                            // B*NC*D f32 = 1.05 MB
    float* scanM = out + (size_t)BATCH * NC * D;   // 1.05 MB
    float* scanP = scanM + (size_t)BATCH * NC * D; // 2 KB

    bf16* WupdT = wb;                 // 512x512
    bf16* WfT   = wb + 262144;        // 512x512
    bf16* W1T   = wb + 524288;        // per layer 2048x512 (F x D)
    bf16* W2T   = wb + 4718592;       // per layer 512x2048 (D x F)
    bf16* HWT   = wb + 8912896;       // 256x512

    dim3 tb(32, 8);
    convT_kernel<<<dim3(16, 16, 2), tb, 0, stream>>>(W_upd, WupdT, D, D,
                                                     (size_t)(W_f - W_upd), 262144);
    convT_kernel<<<dim3(16, 64, N_LAYERS), tb, 0, stream>>>(cW1, W1T, D, F,
                                                            (size_t)D * F, 1048576);
    convT_kernel<<<dim3(64, 16, N_LAYERS), tb, 0, stream>>>(cW2, W2T, F, D,
                                                            (size_t)F * D, 1048576);
    convT_kernel<<<dim3(16, 8, 1), tb, 0, stream>>>(head_W, HWT, D, V, 0, 0);

    // 1. embedding (f32 + bf16)
    embed_kernel<<<M, 128, 0, stream>>>(tokens, emb, xf, lnb);

    // 2. fast memory
    gemm_u<<<dim3(M / 64, D / 256), 512, 0, stream>>>(
        lnb, WupdT, b_upd, nullptr, nullptr, ub, D, D);
    scanA_kernel<<<BATCH * NC * 2, 256, 0, stream>>>(ub, tokens, decayp, scanL, scanP);
    scanB_kernel<<<BATCH * 2, 256, 0, stream>>>(scanL, scanP, scanM);
    scanC_kernel<<<BATCH * NC * 2, 256, 0, stream>>>(ub, tokens, decayp, scanM);
    gemm_resf<<<dim3(M / 64, D / 256), 512, 0, stream>>>(
        ub, WfT, b_f, xf, xf, nullptr, D, D);
    // fused: xf = LN_norm(xf); lnb = LN_cms0(xf)
    ln_fused_kernel<<<M / 4, 256, 0, stream>>>(xf, lnb, norm_g, norm_b,
                                               cms_g, cms_b);

    // 3. CMS layers
    for (int l = 0; l < N_LAYERS; ++l) {
        if (l > 0)
            ln_b16_kernel<<<M / 4, 256, 0, stream>>>(xf, lnb,
                                                     cms_g + (size_t)l * D,
                                                     cms_b + (size_t)l * D);
        bool last = (l == N_LAYERS - 1);
        for (int mc = 0; mc < M; mc += MC) {
            gemm_gelu<<<dim3(MC / 256, F / 256), 512, 0, stream>>>(
                lnb + (size_t)mc * D, W1T + (size_t)l * 1048576,
                cb1 + (size_t)l * F, nullptr, nullptr, hb, F, D);
            if (last)
                gemm_resboth<<<dim3(MC / 128, D / 256), 512, 0, stream>>>(
                    hb, W2T + (size_t)l * 1048576, cb2 + (size_t)l * D,
                    xf + (size_t)mc * D, xf + (size_t)mc * D,
                    lnb + (size_t)mc * D, D, F);
            else
                gemm_res<<<dim3(MC / 128, D / 256), 512, 0, stream>>>(
                    hb, W2T + (size_t)l * 1048576, cb2 + (size_t)l * D,
                    xf + (size_t)mc * D, xf + (size_t)mc * D, nullptr, D, F);
        }
    }

    // 4. head (reads bf16 copy written by last W2 epilogue)
    gemm_plain<<<dim3(M / 64, V / 256), 512, 0, stream>>>(
        lnb, HWT, head_b, nullptr, out, nullptr, V, D);
}

// Round 19
// 530.902 us; speedup vs baseline: 1.0230x; 1.0230x over previous
//
#include <hip/hip_runtime.h>
#include <hip/hip_bf16.h>
#include <math.h>

#define D_MODEL 512
#define N_LAYERS 4
#define SEQ 2048
#define BATCH 8
#define M_TOT (BATCH * SEQ)   // 16384
#define DFF 2048
#define HEAD_V 256
#define SC 32                 // scan chunk
#define NC (SEQ / SC)         // 64 chunks

typedef __hip_bfloat16 bf16;
typedef __bf16 bf16x8 __attribute__((ext_vector_type(8)));
typedef float f32x4 __attribute__((ext_vector_type(4)));

__device__ __forceinline__ unsigned short bfbits(float x) {
    bf16 h = __float2bfloat16(x);
    return *(unsigned short*)&h;
}
__device__ __forceinline__ unsigned int pk(float a, float b) {
    return (unsigned int)bfbits(a) | ((unsigned int)bfbits(b) << 16);
}

// fast GELU (sigmoid form): max abs err vs exact ~3e-3 (validated r9-r18, absmax 0.0156)
__device__ __forceinline__ float gelu_f(float x) {
    float t2 = 1.5957691216f * (x + 0.044715f * x * x * x);
    float e = __expf(t2);
    return x - x * __builtin_amdgcn_rcpf(e + 1.0f);
}

// ---------- weight convert + transpose: W (R x C) f32 -> WT (C x R) bf16 ----
__global__ void convT_kernel(const float* __restrict__ W, bf16* __restrict__ WT,
                             int R, int C, size_t wstride, size_t tstride) {
    W += (size_t)blockIdx.z * wstride;
    WT += (size_t)blockIdx.z * tstride;
    __shared__ float t[32][33];
    int r0 = blockIdx.x * 32, c0 = blockIdx.y * 32;
    int tx = threadIdx.x, ty = threadIdx.y;  // 32 x 8
    #pragma unroll
    for (int i = 0; i < 32; i += 8)
        t[ty + i][tx] = W[(size_t)(r0 + ty + i) * C + c0 + tx];
    __syncthreads();
    #pragma unroll
    for (int i = 0; i < 32; i += 8)
        WT[(size_t)(c0 + ty + i) * R + r0 + tx] = __float2bfloat16(t[tx][ty + i]);
}

// ---------- embedding: x f32 + x bf16 --------------------------------------
__global__ void embed_kernel(const int* __restrict__ tokens,
                             const float* __restrict__ emb,
                             float* __restrict__ xf, bf16* __restrict__ xb) {
    int row = blockIdx.x, t = threadIdx.x;  // 128 threads
    int tok = tokens[row];
    float4 v = ((const float4*)(emb + (size_t)tok * D_MODEL))[t];
    ((float4*)(xf + (size_t)row * D_MODEL))[t] = v;
    uint2 st; st.x = pk(v.x, v.y); st.y = pk(v.z, v.w);
    ((uint2*)(xb + (size_t)row * D_MODEL))[t] = st;
}

// ---------- 3-phase parallel masked scan over S -----------------------------
__global__ void scanA_kernel(bf16* __restrict__ u, const int* __restrict__ tokens,
                             const float* __restrict__ decayp,
                             float* __restrict__ L, float* __restrict__ P) {
    int idx = blockIdx.x;                 // B*NC*2 blocks
    int dblk = idx & 1;
    int c = (idx >> 1) & (NC - 1);
    int b = idx >> 7;                     // NC*2 = 128
    int d = dblk * 256 + threadIdx.x;
    float decay = 1.0f / (1.0f + __expf(-decayp[0]));
    const int* tok = tokens + (size_t)b * SEQ + c * SC;
    bf16* up = u + ((size_t)b * SEQ + (size_t)c * SC) * D_MODEL + d;
    float mem = 0.0f;
    #pragma unroll 4
    for (int s = 0; s < SC; ++s) {
        float ui = __bfloat162float(up[(size_t)s * D_MODEL]);
        bool m = (tok[s] != 0);
        mem = (m ? decay : 1.0f) * mem + (m ? ui : 0.0f);
        up[(size_t)s * D_MODEL] = __float2bfloat16(mem);
    }
    L[((size_t)b * NC + c) * D_MODEL + d] = mem;
    if (threadIdx.x == 0 && dblk == 0) {
        int cnt = 0;
        for (int s = 0; s < SC; ++s) cnt += (tok[s] != 0);
        P[b * NC + c] = __powf(decay, (float)cnt);
    }
}

__global__ void scanB_kernel(const float* __restrict__ L, const float* __restrict__ P,
                             float* __restrict__ Mc) {
    int b = blockIdx.x >> 1;              // B*2 blocks
    int d = (blockIdx.x & 1) * 256 + threadIdx.x;
    float carry = 0.0f;
    for (int c = 0; c < NC; ++c) {
        size_t off = ((size_t)b * NC + c) * D_MODEL + d;
        Mc[off] = carry;
        carry = P[b * NC + c] * carry + L[off];
    }
}

__global__ void scanC_kernel(bf16* __restrict__ u, const int* __restrict__ tokens,
                             const float* __restrict__ decayp,
                             const float* __restrict__ Mc) {
    int idx = blockIdx.x;
    int dblk = idx & 1;
    int c = (idx >> 1) & (NC - 1);
    int b = idx >> 7;
    if (c == 0) return;
    int d = dblk * 256 + threadIdx.x;
    float decay = 1.0f / (1.0f + __expf(-decayp[0]));
    const int* tok = tokens + (size_t)b * SEQ + c * SC;
    bf16* up = u + ((size_t)b * SEQ + (size_t)c * SC) * D_MODEL + d;
    float carry = Mc[((size_t)b * NC + c) * D_MODEL + d];
    float coeff = 1.0f;
    #pragma unroll 4
    for (int s = 0; s < SC; ++s) {
        bool m = (tok[s] != 0);
        coeff *= (m ? decay : 1.0f);
        float local = __bfloat162float(up[(size_t)s * D_MODEL]);
        up[(size_t)s * D_MODEL] = __float2bfloat16(local + carry * coeff);
    }
}

// ---------- LayerNorm body + non-template wrappers --------------------------
__device__ __forceinline__ void ln_body(const float* __restrict__ in,
                                        float* __restrict__ outf,
                                        bf16* __restrict__ outb,
                                        const float* __restrict__ g,
                                        const float* __restrict__ b,
                                        int WF, int WB) {
    int w = threadIdx.x >> 6, lane = threadIdx.x & 63;
    int row = blockIdx.x * 4 + w;
    const float4* ip = (const float4*)(in + (size_t)row * D_MODEL);
    float4 v0 = ip[lane * 2], v1 = ip[lane * 2 + 1];
    float s1 = v0.x + v0.y + v0.z + v0.w + v1.x + v1.y + v1.z + v1.w;
    float s2 = v0.x * v0.x + v0.y * v0.y + v0.z * v0.z + v0.w * v0.w +
               v1.x * v1.x + v1.y * v1.y + v1.z * v1.z + v1.w * v1.w;
    #pragma unroll
    for (int off = 32; off; off >>= 1) {
        s1 += __shfl_xor(s1, off);
        s2 += __shfl_xor(s2, off);
    }
    float mu = s1 * (1.0f / D_MODEL);
    float var = s2 * (1.0f / D_MODEL) - mu * mu;
    float rstd = rsqrtf(var + 1e-5f);
    const float4* g4 = (const float4*)g;
    const float4* b4 = (const float4*)b;
    float4 g0 = g4[lane * 2], g1 = g4[lane * 2 + 1];
    float4 b0 = b4[lane * 2], b1 = b4[lane * 2 + 1];
    float4 o0, o1;
    o0.x = (v0.x - mu) * rstd * g0.x + b0.x;
    o0.y = (v0.y - mu) * rstd * g0.y + b0.y;
    o0.z = (v0.z - mu) * rstd * g0.z + b0.z;
    o0.w = (v0.w - mu) * rstd * g0.w + b0.w;
    o1.x = (v1.x - mu) * rstd * g1.x + b1.x;
    o1.y = (v1.y - mu) * rstd * g1.y + b1.y;
    o1.z = (v1.z - mu) * rstd * g1.z + b1.z;
    o1.w = (v1.w - mu) * rstd * g1.w + b1.w;
    if (WF) {
        float4* op = (float4*)(outf + (size_t)row * D_MODEL);
        op[lane * 2] = o0; op[lane * 2 + 1] = o1;
    }
    if (WB) {
        uint4 st;
        st.x = pk(o0.x, o0.y); st.y = pk(o0.z, o0.w);
        st.z = pk(o1.x, o1.y); st.w = pk(o1.z, o1.w);
        ((uint4*)(outb + (size_t)row * D_MODEL))[lane] = st;
    }
}

__global__ void ln_b16_kernel(const float* __restrict__ in, bf16* __restrict__ outb,
                              const float* __restrict__ g, const float* __restrict__ b) {
    ln_body(in, nullptr, outb, g, b, 0, 1);
}

// Fused: xf = LN_norm(xf); lnb = LN_cms0(LN_norm(xf)).
__global__ void ln_fused_kernel(float* __restrict__ xf, bf16* __restrict__ outb,
                                const float* __restrict__ g0, const float* __restrict__ b0,
                                const float* __restrict__ g1, const float* __restrict__ b1) {
    int w = threadIdx.x >> 6, lane = threadIdx.x & 63;
    int row = blockIdx.x * 4 + w;
    float4* xp = (float4*)(xf + (size_t)row * D_MODEL);
    float4 v0 = xp[lane * 2], v1 = xp[lane * 2 + 1];
    float s1 = v0.x + v0.y + v0.z + v0.w + v1.x + v1.y + v1.z + v1.w;
    float s2 = v0.x * v0.x + v0.y * v0.y + v0.z * v0.z + v0.w * v0.w +
               v1.x * v1.x + v1.y * v1.y + v1.z * v1.z + v1.w * v1.w;
    #pragma unroll
    for (int off = 32; off; off >>= 1) {
        s1 += __shfl_xor(s1, off);
        s2 += __shfl_xor(s2, off);
    }
    float mu = s1 * (1.0f / D_MODEL);
    float var = s2 * (1.0f / D_MODEL) - mu * mu;
    float rstd = rsqrtf(var + 1e-5f);
    const float4* g4 = (const float4*)g0;
    const float4* b4 = (const float4*)b0;
    float4 ga = g4[lane * 2], gb = g4[lane * 2 + 1];
    float4 ba = b4[lane * 2], bb = b4[lane * 2 + 1];
    float4 o0, o1;
    o0.x = (v0.x - mu) * rstd * ga.x + ba.x;
    o0.y = (v0.y - mu) * rstd * ga.y + ba.y;
    o0.z = (v0.z - mu) * rstd * ga.z + ba.z;
    o0.w = (v0.w - mu) * rstd * ga.w + ba.w;
    o1.x = (v1.x - mu) * rstd * gb.x + bb.x;
    o1.y = (v1.y - mu) * rstd * gb.y + bb.y;
    o1.z = (v1.z - mu) * rstd * gb.z + bb.z;
    o1.w = (v1.w - mu) * rstd * gb.w + bb.w;
    xp[lane * 2] = o0; xp[lane * 2 + 1] = o1;
    float t1 = o0.x + o0.y + o0.z + o0.w + o1.x + o1.y + o1.z + o1.w;
    float t2 = o0.x * o0.x + o0.y * o0.y + o0.z * o0.z + o0.w * o0.w +
               o1.x * o1.x + o1.y * o1.y + o1.z * o1.z + o1.w * o1.w;
    #pragma unroll
    for (int off = 32; off; off >>= 1) {
        t1 += __shfl_xor(t1, off);
        t2 += __shfl_xor(t2, off);
    }
    float mu2 = t1 * (1.0f / D_MODEL);
    float var2 = t2 * (1.0f / D_MODEL) - mu2 * mu2;
    float rstd2 = rsqrtf(var2 + 1e-5f);
    const float4* g14 = (const float4*)g1;
    const float4* b14 = (const float4*)b1;
    float4 gc = g14[lane * 2], gd = g14[lane * 2 + 1];
    float4 bc = b14[lane * 2], bd = b14[lane * 2 + 1];
    float4 p0, p1;
    p0.x = (o0.x - mu2) * rstd2 * gc.x + bc.x;
    p0.y = (o0.y - mu2) * rstd2 * gc.y + bc.y;
    p0.z = (o0.z - mu2) * rstd2 * gc.z + bc.z;
    p0.w = (o0.w - mu2) * rstd2 * gc.w + bc.w;
    p1.x = (o1.x - mu2) * rstd2 * gd.x + bd.x;
    p1.y = (o1.y - mu2) * rstd2 * gd.y + bd.y;
    p1.z = (o1.z - mu2) * rstd2 * gd.z + bd.z;
    p1.w = (o1.w - mu2) * rstd2 * gd.w + bd.w;
    uint4 st;
    st.x = pk(p0.x, p0.y); st.y = pk(p0.z, p0.w);
    st.z = pk(p1.x, p1.y); st.w = pk(p1.z, p1.w);
    ((uint4*)(outb + (size_t)row * D_MODEL))[lane] = st;
}

// ---------- bf16 MFMA GEMM: r17 geometry (measured best) + WM=32 head -------
// BN=256, 512 threads, 8 waves (2x4). WM = per-wave rows:
//   WM=128 -> BM=256 (W1)   WM=64 -> BM=128 (fastmem/W2)   WM=32 -> BM=64
//   (head only: grid 256 fills all CUs vs 128 at WM=64)
// Per K-tile: STAGE(t+1) -> counted vmcnt (t's loads done, t+1's in flight)
// -> barrier -> ds_read + MFMA (setprio) -> barrier. 2 buffers.
// Swizzle: LDS row = 128B; 16B-slot s holds chunk s^(row&7); reads XOR same.
#define STAGE(buf, k0)                                                        \
    do {                                                                      \
        _Pragma("unroll")                                                     \
        for (int it = 0; it < AL; ++it) {                                     \
            int cc = tid + it * 512;                                          \
            int rr = cc >> 3, ss = cc & 7;                                    \
            __builtin_amdgcn_global_load_lds(                                 \
                A + (size_t)(m0 + rr) * K + (k0) + 8 * (ss ^ (rr & 7)),       \
                smem + (buf) * TILEB + cc * 16, 16, 0, 0);                    \
        }                                                                     \
        _Pragma("unroll")                                                     \
        for (int it = 0; it < 4; ++it) {                                      \
            int cc = tid + it * 512;                                          \
            int rr = cc >> 3, ss = cc & 7;                                    \
            __builtin_amdgcn_global_load_lds(                                 \
                BT + (size_t)(n0 + rr) * K + (k0) + 8 * (ss ^ (rr & 7)),      \
                smem + (buf) * TILEB + BM * 128 + cc * 16, 16, 0, 0);         \
        }                                                                     \
    } while (0)

template <int WM, int GELU, int RES, int OBF>
__device__ __forceinline__ void gemm_body(char* smem,
                          const bf16* __restrict__ A, const bf16* __restrict__ BT,
                          const float* __restrict__ bias, const float* __restrict__ R,
                          float* __restrict__ Cf, bf16* __restrict__ Cb,
                          int N, int K) {
    constexpr int BM = 2 * WM;
    constexpr int MI = WM / 16;               // m-frags per wave: 8, 4, or 2
    constexpr int MH = (MI >= 4) ? MI / 4 : 1;
    constexpr int MW = (MI >= 4) ? 4 : MI;    // frags per MFMA cluster
    constexpr int AL = (BM >= 64) ? BM / 64 : 1;  // A gload per thread per tile
    constexpr int TILEB = (BM + 256) * 128;   // bytes per LDS buffer
    constexpr int ST = 68;                    // epilogue LDS row stride (floats)
    const int tid = threadIdx.x;
    const int lane = tid & 63;
    const int w = tid >> 6;
    const int wr = w >> 2, wc = w & 3;        // 2 x 4 wave grid
    const int lm = lane & 15, lk = lane >> 4;
    const int swz = (lm & 7) << 4;
    const int m0 = blockIdx.x * BM, n0 = blockIdx.y * 256;

    f32x4 acc[MI][4] = {};
    const int nt = K >> 6;

    STAGE(0, 0);
    int cur = 0;
    for (int t = 0; t < nt; ++t) {
        if (t + 1 < nt) {
            STAGE(cur ^ 1, (t + 1) * 64);
            if constexpr (AL == 4)      asm volatile("s_waitcnt vmcnt(8)" ::: "memory");
            else if constexpr (AL == 2) asm volatile("s_waitcnt vmcnt(6)" ::: "memory");
            else                        asm volatile("s_waitcnt vmcnt(5)" ::: "memory");
        } else {
            asm volatile("s_waitcnt vmcnt(0)" ::: "memory");
        }
        __builtin_amdgcn_s_barrier();
        __builtin_amdgcn_sched_barrier(0);
        const char* Ab = smem + cur * TILEB;
        const char* Bb = Ab + BM * 128;
        #pragma unroll
        for (int ks = 0; ks < 2; ++ks) {
            bf16x8 fb[4];
            #pragma unroll
            for (int nf = 0; nf < 4; ++nf)
                fb[nf] = *(const bf16x8*)(Bb + (wc * 64 + nf * 16 + lm) * 128 +
                                          ((ks * 64 + lk * 16) ^ swz));
            #pragma unroll
            for (int mh = 0; mh < MH; ++mh) {
                bf16x8 fa[MW];
                #pragma unroll
                for (int mf = 0; mf < MW; ++mf)
                    fa[mf] = *(const bf16x8*)(Ab + (wr * WM + (mh * MW + mf) * 16 + lm) * 128 +
                                              ((ks * 64 + lk * 16) ^ swz));
                __builtin_amdgcn_s_setprio(1);
                #pragma unroll
                for (int mf = 0; mf < MW; ++mf)
                    #pragma unroll
                    for (int nf = 0; nf < 4; ++nf)
                        acc[mh * MW + mf][nf] = __builtin_amdgcn_mfma_f32_16x16x32_bf16(
                            fa[mf], fb[nf], acc[mh * MW + mf][nf], 0, 0, 0);
                __builtin_amdgcn_s_setprio(0);
            }
        }
        __builtin_amdgcn_s_barrier();
        cur ^= 1;
    }
    __syncthreads();

    // ---- epilogue: per-wave LDS round-trip for coalesced stores ----
    float* ep = (float*)smem + w * 16 * ST;
    const int r2 = lane >> 2;        // local row 0..15
    const int q = lane & 3;          // 16-col group
    const int gc0 = n0 + wc * 64 + q * 16;
    #pragma unroll
    for (int i = 0; i < MI; ++i) {
        #pragma unroll
        for (int nf = 0; nf < 4; ++nf)
            #pragma unroll
            for (int r = 0; r < 4; ++r)
                ep[(lk * 4 + r) * ST + nf * 16 + lm] = acc[i][nf][r];
        int grow = m0 + wr * WM + i * 16 + r2;
        float4 fx[4];
        #pragma unroll
        for (int v = 0; v < 4; ++v)
            fx[v] = *(const float4*)&ep[r2 * ST + q * 16 + v * 4];
        #pragma unroll
        for (int v = 0; v < 4; ++v) {
            float4 bb = *(const float4*)(bias + gc0 + v * 4);
            fx[v].x += bb.x; fx[v].y += bb.y; fx[v].z += bb.z; fx[v].w += bb.w;
            if (GELU) {
                fx[v].x = gelu_f(fx[v].x);
                fx[v].y = gelu_f(fx[v].y);
                fx[v].z = gelu_f(fx[v].z);
                fx[v].w = gelu_f(fx[v].w);
            }
            if (RES) {
                float4 rr = *(const float4*)(R + (size_t)grow * N + gc0 + v * 4);
                fx[v].x += rr.x; fx[v].y += rr.y; fx[v].z += rr.z; fx[v].w += rr.w;
            }
        }
        if (OBF == 0 || OBF == 2) {
            #pragma unroll
            for (int v = 0; v < 4; ++v)
                *(float4*)(Cf + (size_t)grow * N + gc0 + v * 4) = fx[v];
        }
        if (OBF >= 1) {
            uint4 s1, s2;
            s1.x = pk(fx[0].x, fx[0].y); s1.y = pk(fx[0].z, fx[0].w);
            s1.z = pk(fx[1].x, fx[1].y); s1.w = pk(fx[1].z, fx[1].w);
            s2.x = pk(fx[2].x, fx[2].y); s2.y = pk(fx[2].z, fx[2].w);
            s2.z = pk(fx[3].x, fx[3].y); s2.w = pk(fx[3].z, fx[3].w);
            *(uint4*)(Cb + (size_t)grow * N + gc0) = s1;
            *(uint4*)(Cb + (size_t)grow * N + gc0 + 8) = s2;
        }
    }
}

#define DEF_GEMM(name, WM, GELU, RES, OBF)                                    \
__launch_bounds__(512) __global__ void name(                                  \
        const bf16* __restrict__ A, const bf16* __restrict__ BT,              \
        const float* __restrict__ bias, const float* __restrict__ R,          \
        float* __restrict__ Cf, bf16* __restrict__ Cb, int N, int K) {        \
    __shared__ char smem[2 * ((2 * (WM)) + 256) * 128];                       \
    gemm_body<WM, GELU, RES, OBF>(smem, A, BT, bias, R, Cf, Cb, N, K);        \
}

DEF_GEMM(gemm_gelu,    128, 1, 0, 1)   // W1: 256x256, GELU, bf16 out
DEF_GEMM(gemm_u,        64, 0, 0, 1)   // fastmem u: 128x256, bf16 out
DEF_GEMM(gemm_res,      64, 0, 1, 0)   // W2/fastmem: 128x256, f32 + residual
DEF_GEMM(gemm_resboth,  64, 0, 1, 2)   // last W2: residual, f32+bf16 out
DEF_GEMM(gemm_plain,    32, 0, 0, 0)   // head: 64x256, grid 256 (full GPU)

extern "C" void kernel_launch(void* const* d_in, const int* in_sizes, int n_in,
                              void* d_out, int out_size, void* d_ws, size_t ws_size,
                              hipStream_t stream) {
    const int*   tokens = (const int*)d_in[0];
    const float* emb    = (const float*)d_in[1];
    const float* W_upd  = (const float*)d_in[2];
    const float* b_upd  = (const float*)d_in[3];
    const float* W_f    = (const float*)d_in[4];
    const float* b_f    = (const float*)d_in[5];
    const float* decayp = (const float*)d_in[6];
    const float* norm_g = (const float*)d_in[7];
    const float* norm_b = (const float*)d_in[8];
    const float* cms_g  = (const float*)d_in[9];
    const float* cms_b  = (const float*)d_in[10];
    const float* cW1    = (const float*)d_in[11];
    const float* cb1    = (const float*)d_in[12];
    const float* cW2    = (const float*)d_in[13];
    const float* cb2    = (const float*)d_in[14];
    const float* head_W = (const float*)d_in[15];
    const float* head_b = (const float*)d_in[16];
    float* out = (float*)d_out;

    const int M = M_TOT, D = D_MODEL, F = DFF, V = HEAD_V;

    // ---- workspace layout ----
    float* xf = (float*)d_ws;                                   // 33.55 MB f32 residual
    bf16*  lnb = (bf16*)((char*)d_ws + (size_t)M * D * 4);      // 16.78 MB bf16 A-operand
    bf16*  wb  = (bf16*)((char*)lnb + (size_t)M * D * 2);       // 18.09 MB bf16 weights^T
    const size_t WB_ELEMS = 9043968;
    char* dyn = (char*)wb + WB_ELEMS * 2;
    size_t used = (size_t)(dyn - (char*)d_ws);
    size_t avail = ws_size > used ? ws_size - used : 0;
    int MC = 4096;
    if (avail >= (size_t)16384 * F * 2) MC = 16384;
    else if (avail >= (size_t)8192 * F * 2) MC = 8192;
    bf16* ub = (bf16*)dyn;   // fastmem u/mems (M x D bf16), dead before layers
    bf16* hb = (bf16*)dyn;   // hidden chunk (MC x F bf16)

    // scan scratch lives in d_out (head GEMM fully overwrites it later)
    float* scanL = out;                            // B*NC*D f32 = 1.05 MB
    float* scanM = out + (size_t)BATCH * NC * D;   // 1.05 MB
    float* scanP = scanM + (size_t)BATCH * NC * D; // 2 KB

    bf16* WupdT = wb;                 // 512x512
    bf16* WfT   = wb + 262144;        // 512x512
    bf16* W1T   = wb + 524288;        // per layer 2048x512 (F x D)
    bf16* W2T   = wb + 4718592;       // per layer 512x2048 (D x F)
    bf16* HWT   = wb + 8912896;       // 256x512

    dim3 tb(32, 8);
    convT_kernel<<<dim3(16, 16, 2), tb, 0, stream>>>(W_upd, WupdT, D, D,
                                                     (size_t)(W_f - W_upd), 262144);
    convT_kernel<<<dim3(16, 64, N_LAYERS), tb, 0, stream>>>(cW1, W1T, D, F,
                                                            (size_t)D * F, 1048576);
    convT_kernel<<<dim3(64, 16, N_LAYERS), tb, 0, stream>>>(cW2, W2T, F, D,
                                                            (size_t)F * D, 1048576);
    convT_kernel<<<dim3(16, 8, 1), tb, 0, stream>>>(head_W, HWT, D, V, 0, 0);

    // 1. embedding (f32 + bf16)
    embed_kernel<<<M, 128, 0, stream>>>(tokens, emb, xf, lnb);

    // 2. fast memory
    gemm_u<<<dim3(M / 128, D / 256), 512, 0, stream>>>(
        lnb, WupdT, b_upd, nullptr, nullptr, ub, D, D);
    scanA_kernel<<<BATCH * NC * 2, 256, 0, stream>>>(ub, tokens, decayp, scanL, scanP);
    scanB_kernel<<<BATCH * 2, 256, 0, stream>>>(scanL, scanP, scanM);
    scanC_kernel<<<BATCH * NC * 2, 256, 0, stream>>>(ub, tokens, decayp, scanM);
    gemm_res<<<dim3(M / 128, D / 256), 512, 0, stream>>>(
        ub, WfT, b_f, xf, xf, nullptr, D, D);
    // fused: xf = LN_norm(xf); lnb = LN_cms0(xf)
    ln_fused_kernel<<<M / 4, 256, 0, stream>>>(xf, lnb, norm_g, norm_b,
                                               cms_g, cms_b);

    // 3. CMS layers
    for (int l = 0; l < N_LAYERS; ++l) {
        if (l > 0)
            ln_b16_kernel<<<M / 4, 256, 0, stream>>>(xf, lnb,
                                                     cms_g + (size_t)l * D,
                                                     cms_b + (size_t)l * D);
        bool last = (l == N_LAYERS - 1);
        for (int mc = 0; mc < M; mc += MC) {
            gemm_gelu<<<dim3(MC / 256, F / 256), 512, 0, stream>>>(
                lnb + (size_t)mc * D, W1T + (size_t)l * 1048576,
                cb1 + (size_t)l * F, nullptr, nullptr, hb, F, D);
            if (last)
                gemm_resboth<<<dim3(MC / 128, D / 256), 512, 0, stream>>>(
                    hb, W2T + (size_t)l * 1048576, cb2 + (size_t)l * D,
                    xf + (size_t)mc * D, xf + (size_t)mc * D,
                    lnb + (size_t)mc * D, D, F);
            else
                gemm_res<<<dim3(MC / 128, D / 256), 512, 0, stream>>>(
                    hb, W2T + (size_t)l * 1048576, cb2 + (size_t)l * D,
                    xf + (size_t)mc * D, xf + (size_t)mc * D, nullptr, D, F);
        }
    }

    // 4. head (reads bf16 copy written by last W2 epilogue)
    gemm_plain<<<dim3(M / 64, V / 256), 512, 0, stream>>>(
        lnb, HWT, head_b, nullptr, out, nullptr, V, D);
}